// Round 1
// 6974.716 us; speedup vs baseline: 1.2631x; 1.2631x over previous
//
#include <hip/hip_runtime.h>
#include <cstdint>
#include <cstddef>

#define SEQ 1024
#define DMODEL 768
#define NHEAD 12
#define DHEAD 64
#define NLAYER 4
#define NEXP 8
#define DHID 1536
#define VOCAB 512
#define NTOK 4096   // B*S

// ---------------- embed ----------------
__global__ __launch_bounds__(256) void embed_kernel(const int* __restrict__ x,
    const float* __restrict__ tok, const float* __restrict__ pos, float* __restrict__ h) {
  int i = blockIdx.x * 256 + threadIdx.x;  // over NTOK*DMODEL
  int n = i / DMODEL, d = i - n * DMODEL;
  int s = n & (SEQ - 1);
  h[i] = tok[(size_t)x[n] * DMODEL + d] + pos[(size_t)s * DMODEL + d];
}

// ---------------- layernorm (one block per row) ----------------
__global__ __launch_bounds__(256) void ln_kernel(const float* __restrict__ x,
    const float* __restrict__ g, const float* __restrict__ b, float* __restrict__ y) {
  int row = blockIdx.x;
  const float* xr = x + (size_t)row * DMODEL;
  int t = threadIdx.x;
  float v0 = xr[t], v1 = xr[t + 256], v2 = xr[t + 512];
  float s = v0 + v1 + v2;
  float s2 = v0 * v0 + v1 * v1 + v2 * v2;
  for (int off = 32; off; off >>= 1) { s += __shfl_down(s, off); s2 += __shfl_down(s2, off); }
  __shared__ float rs[4], rq[4];
  if ((t & 63) == 0) { rs[t >> 6] = s; rq[t >> 6] = s2; }
  __syncthreads();
  float S  = rs[0] + rs[1] + rs[2] + rs[3];
  float S2 = rq[0] + rq[1] + rq[2] + rq[3];
  float m = S * (1.f / DMODEL);
  float var = S2 * (1.f / DMODEL) - m * m;
  float r = rsqrtf(var + 1e-5f);
  float* yr = y + (size_t)row * DMODEL;
  yr[t]       = (v0 - m) * r * g[t]       + b[t];
  yr[t + 256] = (v1 - m) * r * g[t + 256] + b[t + 256];
  yr[t + 512] = (v2 - m) * r * g[t + 512] + b[t + 512];
}

// ---------------- tiled fp32 GEMM: C[M,N] = A[M,K] @ B(+bias) ----------------
// 128x128 tile, 256 threads, 8x8 per thread (two 4x4 quadrants spaced 64 apart).
// LDS rows padded +4 floats: rows stay 16B-aligned -> all fragment reads are
// ds_read_b128; transposed staging stores are 2-way (free) bank aliasing.
#define BM 128
#define BN 128
#define BK 16

template<bool TRANSB, bool RESID>
__global__ __launch_bounds__(256, 4) void gemm_std(
    const float* __restrict__ A, const float* __restrict__ Bm,
    const float* __restrict__ bias, float* __restrict__ C,
    int M, int Nn, int K)
{
  __shared__ __align__(16) float As[BK][BM + 4];   // As[k][m]
  __shared__ __align__(16) float Bs[BK][BN + 4];   // Bs[k][n]
  int bm = blockIdx.y * BM, bn = blockIdx.x * BN;
  int tid = threadIdx.x;
  int tr = tid >> 4, tc = tid & 15;
  int ar  = tid >> 2;          // staging row/col (0..63)
  int akc = (tid & 3) << 2;    // staging k offset {0,4,8,12}
  int bkr = tid >> 5;          // dense-B staging k row (0..7)
  int bc  = (tid & 31) << 2;   // dense-B staging col (0..124)
  float acc[8][8] = {};
  for (int k0 = 0; k0 < K; k0 += BK) {
#pragma unroll
    for (int h = 0; h < 2; h++) {            // A: [128 rows]x[16 k] transposed into LDS
      int r = ar + h * 64;
      float4 v = *(const float4*)&A[(size_t)(bm + r) * K + k0 + akc];
      As[akc + 0][r] = v.x; As[akc + 1][r] = v.y;
      As[akc + 2][r] = v.z; As[akc + 3][r] = v.w;
    }
    if (TRANSB) {
#pragma unroll
      for (int h = 0; h < 2; h++) {          // B^T: gather rows of Bm along K
        int c = ar + h * 64;
        float4 v = *(const float4*)&Bm[(size_t)(bn + c) * K + k0 + akc];
        Bs[akc + 0][c] = v.x; Bs[akc + 1][c] = v.y;
        Bs[akc + 2][c] = v.z; Bs[akc + 3][c] = v.w;
      }
    } else {
#pragma unroll
      for (int h = 0; h < 2; h++) {          // B: contiguous rows, float4 straight in
        int r = bkr + h * 8;
        float4 v = *(const float4*)&Bm[(size_t)(k0 + r) * Nn + bn + bc];
        *(float4*)&Bs[r][bc] = v;
      }
    }
    __syncthreads();
#pragma unroll
    for (int kk = 0; kk < BK; kk++) {
      float4 a0 = *(const float4*)&As[kk][tr * 4];
      float4 a1 = *(const float4*)&As[kk][64 + tr * 4];
      float4 b0 = *(const float4*)&Bs[kk][tc * 4];
      float4 b1 = *(const float4*)&Bs[kk][64 + tc * 4];
      float av[8] = {a0.x, a0.y, a0.z, a0.w, a1.x, a1.y, a1.z, a1.w};
      float bv[8] = {b0.x, b0.y, b0.z, b0.w, b1.x, b1.y, b1.z, b1.w};
#pragma unroll
      for (int i = 0; i < 8; i++)
#pragma unroll
        for (int j = 0; j < 8; j++) acc[i][j] += av[i] * bv[j];
    }
    __syncthreads();
  }
#pragma unroll
  for (int hi = 0; hi < 2; hi++)
#pragma unroll
    for (int i = 0; i < 4; i++) {
      int r = bm + hi * 64 + tr * 4 + i;
      float* Crow = C + (size_t)r * Nn;
#pragma unroll
      for (int hj = 0; hj < 2; hj++)
#pragma unroll
        for (int j = 0; j < 4; j++) {
          int c = bn + hj * 64 + tc * 4 + j;
          float v = acc[hi * 4 + i][hj * 4 + j] + (bias ? bias[c] : 0.f);
          if (RESID) v += Crow[c];
          Crow[c] = v;
        }
    }
}

// ---------------- MoE gathered GEMM ----------------
__device__ __forceinline__ float gelu_f(float x) {
  float x3 = x * x * x;
  return 0.5f * x * (1.f + tanhf(0.7978845608028654f * (x + 0.044715f * x3)));
}

template<bool GELU, bool SCALE>
__global__ __launch_bounds__(256, 4) void gemm_moe(
    const float* __restrict__ A, const float* __restrict__ Bbase,
    const float* __restrict__ biasBase, float* __restrict__ C,
    const int* __restrict__ entries, const int* __restrict__ counts,
    const float* __restrict__ tokw, int Nn, int K)
{
  int e = blockIdx.z;
  int cnt = counts[e];
  int bm = blockIdx.y * BM;
  if (bm >= cnt) return;
  const float* Bm = Bbase + (size_t)e * K * Nn;
  const float* bias = biasBase + (size_t)e * Nn;
  const int* list = entries + e * NTOK;
  int bn = blockIdx.x * BN;
  int tid = threadIdx.x;
  int tr = tid >> 4, tc = tid & 15;
  int ar  = tid >> 2;
  int akc = (tid & 3) << 2;
  int bkr = tid >> 5;
  int bc  = (tid & 31) << 2;
  __shared__ __align__(16) float As[BK][BM + 4];
  __shared__ __align__(16) float Bs[BK][BN + 4];
  __shared__ int rowent[BM];
  for (int i = tid; i < BM; i += 256) {
    int gr = bm + i;
    rowent[i] = (gr < cnt) ? list[gr] : -1;
  }
  __syncthreads();
  float acc[8][8] = {};
  for (int k0 = 0; k0 < K; k0 += BK) {
#pragma unroll
    for (int h = 0; h < 2; h++) {
      int r = ar + h * 64;
      int ent = rowent[r];
      float4 v = make_float4(0.f, 0.f, 0.f, 0.f);
      if (ent >= 0) {
        int arow = GELU ? (ent >> 1) : ent;  // w1 gathers token rows, w2 gathers H1 rows
        v = *(const float4*)&A[(size_t)arow * K + k0 + akc];
      }
      As[akc + 0][r] = v.x; As[akc + 1][r] = v.y;
      As[akc + 2][r] = v.z; As[akc + 3][r] = v.w;
    }
#pragma unroll
    for (int h = 0; h < 2; h++) {
      int r = bkr + h * 8;
      float4 v = *(const float4*)&Bm[(size_t)(k0 + r) * Nn + bn + bc];
      *(float4*)&Bs[r][bc] = v;
    }
    __syncthreads();
#pragma unroll
    for (int kk = 0; kk < BK; kk++) {
      float4 a0 = *(const float4*)&As[kk][tr * 4];
      float4 a1 = *(const float4*)&As[kk][64 + tr * 4];
      float4 b0 = *(const float4*)&Bs[kk][tc * 4];
      float4 b1 = *(const float4*)&Bs[kk][64 + tc * 4];
      float av[8] = {a0.x, a0.y, a0.z, a0.w, a1.x, a1.y, a1.z, a1.w};
      float bv[8] = {b0.x, b0.y, b0.z, b0.w, b1.x, b1.y, b1.z, b1.w};
#pragma unroll
      for (int i = 0; i < 8; i++)
#pragma unroll
        for (int j = 0; j < 8; j++) acc[i][j] += av[i] * bv[j];
    }
    __syncthreads();
  }
#pragma unroll
  for (int hi = 0; hi < 2; hi++)
#pragma unroll
    for (int i = 0; i < 4; i++) {
      int ent = rowent[hi * 64 + tr * 4 + i];
      if (ent < 0) continue;
      float scl = SCALE ? tokw[ent] : 1.f;
      float* Crow = C + (size_t)ent * Nn;
#pragma unroll
      for (int hj = 0; hj < 2; hj++)
#pragma unroll
        for (int j = 0; j < 4; j++) {
          int c = bn + hj * 64 + tc * 4 + j;
          float v = acc[hi * 4 + i][hj * 4 + j] + bias[c];
          if (GELU) v = gelu_f(v);
          if (SCALE) v *= scl;
          Crow[c] = v;
        }
    }
}

// ---------------- flash attention: one block per (b, h, 64-row q-tile) ----------------
// qkv row layout: [q(768) | k(768) | v(768)], head h occupies cols h*64..h*64+63.
__global__ __launch_bounds__(256) void fattn_kernel(const float* __restrict__ qkv,
                                                    float* __restrict__ out) {
  int qt = blockIdx.x;           // q tile 0..15
  int hh = blockIdx.y;           // head
  int b  = blockIdx.z;           // batch
  int n0 = b * SEQ;
  int q0 = qt * 64;
  const float* base = qkv + (size_t)n0 * (3 * DMODEL);
  int tid = threadIdx.x;
  int tr = tid >> 4, tc = tid & 15;

  __shared__ float Qs[64][65];   // transposed: Qs[d][q], pre-scaled
  __shared__ float Ks[64][65];   // transposed: Ks[d][k]
  __shared__ float Ps[64][65];   // P[q][k]
  __shared__ float Vs[64][64];   // V[k][d]

#pragma unroll
  for (int it = 0; it < 16; it++) {
    int i = tid + it * 256;
    int r = i >> 6, c = i & 63;
    Qs[c][r] = base[(size_t)(q0 + r) * (3 * DMODEL) + hh * DHEAD + c] * 0.125f;
  }

  float m_i[4], l_i[4], O[4][4];
#pragma unroll
  for (int i = 0; i < 4; i++) {
    m_i[i] = -3.4e38f; l_i[i] = 0.f;
#pragma unroll
    for (int j = 0; j < 4; j++) O[i][j] = 0.f;
  }

  for (int kt = 0; kt <= qt; kt++) {
    int k0 = kt * 64;
    __syncthreads();   // previous iteration's Ks/Vs/Ps reads done
#pragma unroll
    for (int it = 0; it < 16; it++) {
      int i = tid + it * 256;
      int r = i >> 6, c = i & 63;
      const float* krow = base + (size_t)(k0 + r) * (3 * DMODEL);
      Ks[c][r] = krow[DMODEL + hh * DHEAD + c];
      Vs[r][c] = krow[2 * DMODEL + hh * DHEAD + c];
    }
    __syncthreads();

    // S = (Q*scale) K^T  — 4x4 per thread
    float s[4][4] = {};
#pragma unroll
    for (int d = 0; d < 64; d++) {
      float a[4], bb[4];
#pragma unroll
      for (int i = 0; i < 4; i++) a[i] = Qs[d][tr * 4 + i];
#pragma unroll
      for (int j = 0; j < 4; j++) bb[j] = Ks[d][tc * 4 + j];
#pragma unroll
      for (int i = 0; i < 4; i++)
#pragma unroll
        for (int j = 0; j < 4; j++) s[i][j] += a[i] * bb[j];
    }
    if (kt == qt) {  // causal mask only on the diagonal tile
#pragma unroll
      for (int i = 0; i < 4; i++)
#pragma unroll
        for (int j = 0; j < 4; j++)
          if (k0 + tc * 4 + j > q0 + tr * 4 + i) s[i][j] = -3.4e38f;
    }

    // online softmax: the 16 lanes with equal tr share each q row
#pragma unroll
    for (int i = 0; i < 4; i++) {
      float rm = fmaxf(fmaxf(s[i][0], s[i][1]), fmaxf(s[i][2], s[i][3]));
#pragma unroll
      for (int off = 1; off < 16; off <<= 1) rm = fmaxf(rm, __shfl_xor(rm, off));
      float mnew = fmaxf(m_i[i], rm);
      float alpha = expf(m_i[i] - mnew);
      float p[4], rsum = 0.f;
#pragma unroll
      for (int j = 0; j < 4; j++) { p[j] = expf(s[i][j] - mnew); rsum += p[j]; }
#pragma unroll
      for (int off = 1; off < 16; off <<= 1) rsum += __shfl_xor(rsum, off);
      l_i[i] = l_i[i] * alpha + rsum;
      m_i[i] = mnew;
#pragma unroll
      for (int j = 0; j < 4; j++) {
        O[i][j] *= alpha;
        Ps[tr * 4 + i][tc * 4 + j] = p[j];
      }
    }
    __syncthreads();

    // O += P V — 4x4 per thread (same tr = same q rows, so alpha bookkeeping is consistent)
#pragma unroll
    for (int kk = 0; kk < 64; kk++) {
      float a[4], bb[4];
#pragma unroll
      for (int i = 0; i < 4; i++) a[i] = Ps[tr * 4 + i][kk];
#pragma unroll
      for (int j = 0; j < 4; j++) bb[j] = Vs[kk][tc * 4 + j];
#pragma unroll
      for (int i = 0; i < 4; i++)
#pragma unroll
        for (int j = 0; j < 4; j++) O[i][j] += a[i] * bb[j];
    }
  }

#pragma unroll
  for (int i = 0; i < 4; i++) {
    float rinv = 1.f / l_i[i];
    float* orow = out + (size_t)(n0 + q0 + tr * 4 + i) * DMODEL + hh * DHEAD;
#pragma unroll
    for (int j = 0; j < 4; j++) orow[tc * 4 + j] = O[i][j] * rinv;
  }
}

// ---------------- gate: 1 thread per token ----------------
__global__ __launch_bounds__(256) void gate_kernel(const float* __restrict__ xln,
    const float* __restrict__ gw, const float* __restrict__ gb,
    int* __restrict__ counts, int* __restrict__ entries, float* __restrict__ tokw) {
  int n = blockIdx.x * 256 + threadIdx.x;
  if (n >= NTOK) return;
  const float* xr = xln + (size_t)n * DMODEL;
  float gl[NEXP];
#pragma unroll
  for (int e = 0; e < NEXP; e++) gl[e] = gb[e];
  for (int dd = 0; dd < DMODEL; dd++) {
    float xv = xr[dd];
#pragma unroll
    for (int e = 0; e < NEXP; e++) gl[e] += xv * gw[dd * NEXP + e];
  }
  float mx = gl[0];
#pragma unroll
  for (int e = 1; e < NEXP; e++) mx = fmaxf(mx, gl[e]);
  float ex[NEXP];
#pragma unroll
  for (int e = 0; e < NEXP; e++) ex[e] = expf(gl[e] - mx);
  int i0 = 0; float v0 = ex[0];
#pragma unroll
  for (int e = 1; e < NEXP; e++) if (ex[e] > v0) { v0 = ex[e]; i0 = e; }
  int i1 = -1; float v1 = -1.f;
#pragma unroll
  for (int e = 0; e < NEXP; e++) if (e != i0 && ex[e] > v1) { v1 = ex[e]; i1 = e; }
  float wsum = v0 + v1;            // softmax denominator cancels in renorm
  float w0 = v0 / wsum, w1 = v1 / wsum;
  int p0 = atomicAdd(&counts[i0], 1);
  entries[i0 * NTOK + p0] = n * 2 + 0;
  tokw[n * 2 + 0] = w0;
  int p1 = atomicAdd(&counts[i1], 1);
  entries[i1 * NTOK + p1] = n * 2 + 1;
  tokw[n * 2 + 1] = w1;
}

__global__ void zero_counts(int* c) { if (threadIdx.x < NEXP) c[threadIdx.x] = 0; }

// ---------------- combine: h += eo[slot0] + eo[slot1] ----------------
__global__ __launch_bounds__(256) void combine_kernel(float* __restrict__ h,
                                                      const float* __restrict__ eo) {
  int i = blockIdx.x * 256 + threadIdx.x;
  int n = i / DMODEL, d = i - n * DMODEL;
  h[i] += eo[(size_t)(n * 2) * DMODEL + d] + eo[(size_t)(n * 2 + 1) * DMODEL + d];
}

extern "C" void kernel_launch(void* const* d_in, const int* in_sizes, int n_in,
                              void* d_out, int out_size, void* d_ws, size_t ws_size,
                              hipStream_t stream) {
  const int*   x       = (const int*)d_in[0];
  const float* tok_emb = (const float*)d_in[1];
  const float* pos_emb = (const float*)d_in[2];
  const float* ln1_g   = (const float*)d_in[3];
  const float* ln1_b   = (const float*)d_in[4];
  const float* qkv_w   = (const float*)d_in[5];
  const float* qkv_b   = (const float*)d_in[6];
  const float* proj_w  = (const float*)d_in[7];
  const float* proj_b  = (const float*)d_in[8];
  const float* ln2_g   = (const float*)d_in[9];
  const float* ln2_b   = (const float*)d_in[10];
  const float* gate_w  = (const float*)d_in[11];
  const float* gate_b  = (const float*)d_in[12];
  const float* w1      = (const float*)d_in[13];
  const float* b1      = (const float*)d_in[14];
  const float* w2      = (const float*)d_in[15];
  const float* b2      = (const float*)d_in[16];
  const float* lnf_g   = (const float*)d_in[17];
  const float* lnf_b   = (const float*)d_in[18];
  float* out = (float*)d_out;

  const size_t ND = (size_t)NTOK * DMODEL;            // 3,145,728 floats
  float* h    = (float*)d_ws;
  float* xln  = h + ND;
  float* R    = xln + ND;                              // qkv (3*ND) / H1 (2N*DHID)
  float* R2   = R + (size_t)2 * NTOK * DHID;           // attn_out (ND) / eo (2N*D)
  float* tokw = R2 + (size_t)2 * NTOK * DMODEL;
  int* counts  = (int*)(tokw + 2 * NTOK);
  int* entries = counts + NEXP;

  float* qkvbuf   = R;
  float* H1       = R;
  float* attn_out = R2;
  float* eo       = R2;

  dim3 blk(256);
  embed_kernel<<<ND / 256, blk, 0, stream>>>(x, tok_emb, pos_emb, h);
  for (int l = 0; l < NLAYER; l++) {
    ln_kernel<<<NTOK, blk, 0, stream>>>(h, ln1_g + l * DMODEL, ln1_b + l * DMODEL, xln);
    gemm_std<false, false><<<dim3(3 * DMODEL / BN, NTOK / BM), blk, 0, stream>>>(
        xln, qkv_w + (size_t)l * DMODEL * 3 * DMODEL, qkv_b + l * 3 * DMODEL,
        qkvbuf, NTOK, 3 * DMODEL, DMODEL);
    fattn_kernel<<<dim3(SEQ / 64, NHEAD, 4), blk, 0, stream>>>(qkvbuf, attn_out);
    gemm_std<false, true><<<dim3(DMODEL / BN, NTOK / BM), blk, 0, stream>>>(
        attn_out, proj_w + (size_t)l * DMODEL * DMODEL, proj_b + l * DMODEL,
        h, NTOK, DMODEL, DMODEL);
    ln_kernel<<<NTOK, blk, 0, stream>>>(h, ln2_g + l * DMODEL, ln2_b + l * DMODEL, xln);
    zero_counts<<<1, 64, 0, stream>>>(counts);
    gate_kernel<<<NTOK / 256, blk, 0, stream>>>(
        xln, gate_w + (size_t)l * DMODEL * NEXP, gate_b + l * NEXP, counts, entries, tokw);
    gemm_moe<true, false><<<dim3(DHID / BN, NTOK / BM, NEXP), blk, 0, stream>>>(
        xln, w1 + (size_t)l * NEXP * DMODEL * DHID, b1 + (size_t)l * NEXP * DHID,
        H1, entries, counts, tokw, DHID, DMODEL);
    gemm_moe<false, true><<<dim3(DMODEL / BN, NTOK / BM, NEXP), blk, 0, stream>>>(
        H1, w2 + (size_t)l * NEXP * DHID * DMODEL, b2 + (size_t)l * NEXP * DMODEL,
        eo, entries, counts, tokw, DMODEL, DHID);
    combine_kernel<<<ND / 256, blk, 0, stream>>>(h, eo);
  }
  ln_kernel<<<NTOK, blk, 0, stream>>>(h, lnf_g, lnf_b, xln);
  gemm_std<true, false><<<dim3(VOCAB / BN, NTOK / BM), blk, 0, stream>>>(
      xln, tok_emb, nullptr, out, NTOK, VOCAB, DMODEL);
}

// Round 2
// 4225.533 us; speedup vs baseline: 2.0850x; 1.6506x over previous
//
#include <hip/hip_runtime.h>
#include <cstdint>
#include <cstddef>

#define SEQ 1024
#define DMODEL 768
#define NHEAD 12
#define DHEAD 64
#define NLAYER 4
#define NEXP 8
#define DHID 1536
#define VOCAB 512
#define NTOK 4096   // B*S

typedef __attribute__((ext_vector_type(4))) float f32x4;
typedef __attribute__((ext_vector_type(8))) unsigned short us8v;
typedef __attribute__((ext_vector_type(8))) __bf16 bf16x8;
union FragU { us8v u; bf16x8 b; };

// ---------------- embed ----------------
__global__ __launch_bounds__(256) void embed_kernel(const int* __restrict__ x,
    const float* __restrict__ tok, const float* __restrict__ pos, float* __restrict__ h) {
  int i = blockIdx.x * 256 + threadIdx.x;  // over NTOK*DMODEL
  int n = i / DMODEL, d = i - n * DMODEL;
  int s = n & (SEQ - 1);
  h[i] = tok[(size_t)x[n] * DMODEL + d] + pos[(size_t)s * DMODEL + d];
}

// ---------------- layernorm (one block per row) ----------------
__global__ __launch_bounds__(256) void ln_kernel(const float* __restrict__ x,
    const float* __restrict__ g, const float* __restrict__ b, float* __restrict__ y) {
  int row = blockIdx.x;
  const float* xr = x + (size_t)row * DMODEL;
  int t = threadIdx.x;
  float v0 = xr[t], v1 = xr[t + 256], v2 = xr[t + 512];
  float s = v0 + v1 + v2;
  float s2 = v0 * v0 + v1 * v1 + v2 * v2;
  for (int off = 32; off; off >>= 1) { s += __shfl_down(s, off); s2 += __shfl_down(s2, off); }
  __shared__ float rs[4], rq[4];
  if ((t & 63) == 0) { rs[t >> 6] = s; rq[t >> 6] = s2; }
  __syncthreads();
  float S  = rs[0] + rs[1] + rs[2] + rs[3];
  float S2 = rq[0] + rq[1] + rq[2] + rq[3];
  float m = S * (1.f / DMODEL);
  float var = S2 * (1.f / DMODEL) - m * m;
  float r = rsqrtf(var + 1e-5f);
  float* yr = y + (size_t)row * DMODEL;
  yr[t]       = (v0 - m) * r * g[t]       + b[t];
  yr[t + 256] = (v1 - m) * r * g[t + 256] + b[t + 256];
  yr[t + 512] = (v2 - m) * r * g[t + 512] + b[t + 512];
}

// ---------------- split-bf16 MFMA GEMM machinery ----------------
// 128x128 tile, 256 threads = 4 waves (2x2), each wave owns a 64x64 sub-tile
// = 4x4 grid of 16x16 fragments. K-step 32. fp32 inputs are split on the fly
// into bf16 hi/lo during LDS staging; acc = Ah*Bh + Ah*Bl + Al*Bh (fp32 acc).
// LDS layout: [row][32 k] bf16 rows of 64B, chunk-XOR-swizzled so both the
// staging ds_write_b128 and the fragment ds_read_b128 are bank-uniform.
#define BM 128
#define BN 128
#define BK 32

__device__ __forceinline__ int chx(int row, int kb) {
  return row * 32 + ((kb ^ ((row >> 1) & 3)) << 3);   // ushort units, 16B chunks
}

__device__ __forceinline__ void cvt8(const f32x4 x0, const f32x4 x1, us8v& h, us8v& l) {
#pragma unroll
  for (int j = 0; j < 4; j++) {
    unsigned int bb = __float_as_uint(x0[j]);
    h[j] = (unsigned short)(bb >> 16);
    float fl = x0[j] - __uint_as_float(bb & 0xffff0000u);
    l[j] = (unsigned short)(__float_as_uint(fl) >> 16);
  }
#pragma unroll
  for (int j = 0; j < 4; j++) {
    unsigned int bb = __float_as_uint(x1[j]);
    h[4 + j] = (unsigned short)(bb >> 16);
    float fl = x1[j] - __uint_as_float(bb & 0xffff0000u);
    l[4 + j] = (unsigned short)(__float_as_uint(fl) >> 16);
  }
}

template<bool TRANSB, bool RESID>
__global__ __launch_bounds__(256, 2) void gemm_mfma(
    const float* __restrict__ A, const float* __restrict__ Bm,
    const float* __restrict__ bias, float* __restrict__ C,
    int M, int Nn, int K)
{
  __shared__ __align__(16) unsigned short AsH[BM * 32], AsL[BM * 32];
  __shared__ __align__(16) unsigned short BsH[BN * 32], BsL[BN * 32];
  int bm = blockIdx.y * BM, bn = blockIdx.x * BN;
  int tid = threadIdx.x;
  int lane = tid & 63;
  int wid = tid >> 6;
  int wr = wid >> 1, wc = wid & 1;
  int frow = lane & 15, fkb = lane >> 4;
  f32x4 zero = {0.f, 0.f, 0.f, 0.f};
  f32x4 acc[4][4];
#pragma unroll
  for (int i = 0; i < 4; i++)
#pragma unroll
    for (int j = 0; j < 4; j++) acc[i][j] = zero;

  int sr = tid & 127;          // staging row (A side) / col (B side)
  bool doB = tid >= 128;

  for (int k0 = 0; k0 < K; k0 += BK) {
    if (!doB) {
      const float* Ap = A + (size_t)(bm + sr) * K + k0;
#pragma unroll
      for (int c = 0; c < 4; c++) {
        f32x4 x0 = *(const f32x4*)(Ap + c * 8);
        f32x4 x1 = *(const f32x4*)(Ap + c * 8 + 4);
        us8v h, l; cvt8(x0, x1, h, l);
        *(us8v*)&AsH[chx(sr, c)] = h;
        *(us8v*)&AsL[chx(sr, c)] = l;
      }
    } else if (TRANSB) {
      const float* Bp = Bm + (size_t)(bn + sr) * K + k0;   // B^T: rows are n, k-contig
#pragma unroll
      for (int c = 0; c < 4; c++) {
        f32x4 x0 = *(const f32x4*)(Bp + c * 8);
        f32x4 x1 = *(const f32x4*)(Bp + c * 8 + 4);
        us8v h, l; cvt8(x0, x1, h, l);
        *(us8v*)&BsH[chx(sr, c)] = h;
        *(us8v*)&BsL[chx(sr, c)] = l;
      }
    } else {
      const float* Bp = Bm + (size_t)k0 * Nn + bn + sr;    // B[k][n]: gather a column
#pragma unroll
      for (int c = 0; c < 4; c++) {
        f32x4 x0, x1;
#pragma unroll
        for (int j = 0; j < 4; j++) x0[j] = Bp[(size_t)(c * 8 + j) * Nn];
#pragma unroll
        for (int j = 0; j < 4; j++) x1[j] = Bp[(size_t)(c * 8 + 4 + j) * Nn];
        us8v h, l; cvt8(x0, x1, h, l);
        *(us8v*)&BsH[chx(sr, c)] = h;
        *(us8v*)&BsL[chx(sr, c)] = l;
      }
    }
    __syncthreads();
    FragU ah[4], al[4], bh[4], bl[4];
#pragma unroll
    for (int i = 0; i < 4; i++) {
      ah[i].u = *(const us8v*)&AsH[chx(wr * 64 + i * 16 + frow, fkb)];
      al[i].u = *(const us8v*)&AsL[chx(wr * 64 + i * 16 + frow, fkb)];
      bh[i].u = *(const us8v*)&BsH[chx(wc * 64 + i * 16 + frow, fkb)];
      bl[i].u = *(const us8v*)&BsL[chx(wc * 64 + i * 16 + frow, fkb)];
    }
#pragma unroll
    for (int i = 0; i < 4; i++)
#pragma unroll
      for (int j = 0; j < 4; j++)
        acc[i][j] = __builtin_amdgcn_mfma_f32_16x16x32_bf16(ah[i].b, bh[j].b, acc[i][j], 0, 0, 0);
#pragma unroll
    for (int i = 0; i < 4; i++)
#pragma unroll
      for (int j = 0; j < 4; j++)
        acc[i][j] = __builtin_amdgcn_mfma_f32_16x16x32_bf16(ah[i].b, bl[j].b, acc[i][j], 0, 0, 0);
#pragma unroll
    for (int i = 0; i < 4; i++)
#pragma unroll
      for (int j = 0; j < 4; j++)
        acc[i][j] = __builtin_amdgcn_mfma_f32_16x16x32_bf16(al[i].b, bh[j].b, acc[i][j], 0, 0, 0);
    __syncthreads();
  }
#pragma unroll
  for (int i = 0; i < 4; i++) {
    int rbase = bm + wr * 64 + i * 16 + (lane >> 4) * 4;
#pragma unroll
    for (int q = 0; q < 4; q++) {
      float* Crow = C + (size_t)(rbase + q) * Nn;
#pragma unroll
      for (int j = 0; j < 4; j++) {
        int col = bn + wc * 64 + j * 16 + frow;
        float v = acc[i][j][q] + (bias ? bias[col] : 0.f);
        if (RESID) v += Crow[col];
        Crow[col] = v;
      }
    }
  }
}

// ---------------- MoE gathered split-bf16 MFMA GEMM ----------------
__device__ __forceinline__ float gelu_f(float x) {
  float x3 = x * x * x;
  return 0.5f * x * (1.f + tanhf(0.7978845608028654f * (x + 0.044715f * x3)));
}

template<bool GELU, bool SCALE>
__global__ __launch_bounds__(256, 2) void gemm_moe_mfma(
    const float* __restrict__ A, const float* __restrict__ Bbase,
    const float* __restrict__ biasBase, float* __restrict__ C,
    const int* __restrict__ entries, const int* __restrict__ counts,
    const float* __restrict__ tokw, int Nn, int K)
{
  int e = blockIdx.z;
  int cnt = counts[e];
  int bm = blockIdx.y * BM;
  if (bm >= cnt) return;
  const float* Bm = Bbase + (size_t)e * K * Nn;
  const float* bias = biasBase + (size_t)e * Nn;
  const int* list = entries + e * NTOK;
  int bn = blockIdx.x * BN;
  int tid = threadIdx.x;
  int lane = tid & 63;
  int wid = tid >> 6;
  int wr = wid >> 1, wc = wid & 1;
  int frow = lane & 15, fkb = lane >> 4;

  __shared__ __align__(16) unsigned short AsH[BM * 32], AsL[BM * 32];
  __shared__ __align__(16) unsigned short BsH[BN * 32], BsL[BN * 32];
  __shared__ int rowent[BM];
  if (tid < BM) {
    int gr = bm + tid;
    rowent[tid] = (gr < cnt) ? list[gr] : -1;
  }
  __syncthreads();

  f32x4 zero = {0.f, 0.f, 0.f, 0.f};
  f32x4 acc[4][4];
#pragma unroll
  for (int i = 0; i < 4; i++)
#pragma unroll
    for (int j = 0; j < 4; j++) acc[i][j] = zero;

  int sr = tid & 127;
  bool doB = tid >= 128;

  for (int k0 = 0; k0 < K; k0 += BK) {
    if (!doB) {
      int ent = rowent[sr];
      if (ent >= 0) {
        int arow = GELU ? (ent >> 1) : ent;  // w1 gathers token rows, w2 gathers H1 rows
        const float* Ap = A + (size_t)arow * K + k0;
#pragma unroll
        for (int c = 0; c < 4; c++) {
          f32x4 x0 = *(const f32x4*)(Ap + c * 8);
          f32x4 x1 = *(const f32x4*)(Ap + c * 8 + 4);
          us8v h, l; cvt8(x0, x1, h, l);
          *(us8v*)&AsH[chx(sr, c)] = h;
          *(us8v*)&AsL[chx(sr, c)] = l;
        }
      } else {
        us8v z = {0, 0, 0, 0, 0, 0, 0, 0};
#pragma unroll
        for (int c = 0; c < 4; c++) {
          *(us8v*)&AsH[chx(sr, c)] = z;
          *(us8v*)&AsL[chx(sr, c)] = z;
        }
      }
    } else {
      const float* Bp = Bm + (size_t)k0 * Nn + bn + sr;
#pragma unroll
      for (int c = 0; c < 4; c++) {
        f32x4 x0, x1;
#pragma unroll
        for (int j = 0; j < 4; j++) x0[j] = Bp[(size_t)(c * 8 + j) * Nn];
#pragma unroll
        for (int j = 0; j < 4; j++) x1[j] = Bp[(size_t)(c * 8 + 4 + j) * Nn];
        us8v h, l; cvt8(x0, x1, h, l);
        *(us8v*)&BsH[chx(sr, c)] = h;
        *(us8v*)&BsL[chx(sr, c)] = l;
      }
    }
    __syncthreads();
    FragU ah[4], al[4], bh[4], bl[4];
#pragma unroll
    for (int i = 0; i < 4; i++) {
      ah[i].u = *(const us8v*)&AsH[chx(wr * 64 + i * 16 + frow, fkb)];
      al[i].u = *(const us8v*)&AsL[chx(wr * 64 + i * 16 + frow, fkb)];
      bh[i].u = *(const us8v*)&BsH[chx(wc * 64 + i * 16 + frow, fkb)];
      bl[i].u = *(const us8v*)&BsL[chx(wc * 64 + i * 16 + frow, fkb)];
    }
#pragma unroll
    for (int i = 0; i < 4; i++)
#pragma unroll
      for (int j = 0; j < 4; j++)
        acc[i][j] = __builtin_amdgcn_mfma_f32_16x16x32_bf16(ah[i].b, bh[j].b, acc[i][j], 0, 0, 0);
#pragma unroll
    for (int i = 0; i < 4; i++)
#pragma unroll
      for (int j = 0; j < 4; j++)
        acc[i][j] = __builtin_amdgcn_mfma_f32_16x16x32_bf16(ah[i].b, bl[j].b, acc[i][j], 0, 0, 0);
#pragma unroll
    for (int i = 0; i < 4; i++)
#pragma unroll
      for (int j = 0; j < 4; j++)
        acc[i][j] = __builtin_amdgcn_mfma_f32_16x16x32_bf16(al[i].b, bh[j].b, acc[i][j], 0, 0, 0);
    __syncthreads();
  }
#pragma unroll
  for (int i = 0; i < 4; i++) {
    int rloc = wr * 64 + i * 16 + (lane >> 4) * 4;
#pragma unroll
    for (int q = 0; q < 4; q++) {
      int ent = rowent[rloc + q];
      if (ent < 0) continue;
      float scl = SCALE ? tokw[ent] : 1.f;
      float* Crow = C + (size_t)ent * Nn;
#pragma unroll
      for (int j = 0; j < 4; j++) {
        int col = bn + wc * 64 + j * 16 + frow;
        float v = acc[i][j][q] + bias[col];
        if (GELU) v = gelu_f(v);
        if (SCALE) v *= scl;
        Crow[col] = v;
      }
    }
  }
}

// ---------------- flash attention: one block per (b, h, 64-row q-tile) ----------------
// qkv row layout: [q(768) | k(768) | v(768)], head h occupies cols h*64..h*64+63.
__global__ __launch_bounds__(256) void fattn_kernel(const float* __restrict__ qkv,
                                                    float* __restrict__ out) {
  int qt = blockIdx.x;           // q tile 0..15
  int hh = blockIdx.y;           // head
  int b  = blockIdx.z;           // batch
  int n0 = b * SEQ;
  int q0 = qt * 64;
  const float* base = qkv + (size_t)n0 * (3 * DMODEL);
  int tid = threadIdx.x;
  int tr = tid >> 4, tc = tid & 15;

  __shared__ float Qs[64][65];   // transposed: Qs[d][q], pre-scaled
  __shared__ float Ks[64][65];   // transposed: Ks[d][k]
  __shared__ float Ps[64][65];   // P[q][k]
  __shared__ float Vs[64][64];   // V[k][d]

#pragma unroll
  for (int it = 0; it < 16; it++) {
    int i = tid + it * 256;
    int r = i >> 6, c = i & 63;
    Qs[c][r] = base[(size_t)(q0 + r) * (3 * DMODEL) + hh * DHEAD + c] * 0.125f;
  }

  float m_i[4], l_i[4], O[4][4];
#pragma unroll
  for (int i = 0; i < 4; i++) {
    m_i[i] = -3.4e38f; l_i[i] = 0.f;
#pragma unroll
    for (int j = 0; j < 4; j++) O[i][j] = 0.f;
  }

  for (int kt = 0; kt <= qt; kt++) {
    int k0 = kt * 64;
    __syncthreads();   // previous iteration's Ks/Vs/Ps reads done
#pragma unroll
    for (int it = 0; it < 16; it++) {
      int i = tid + it * 256;
      int r = i >> 6, c = i & 63;
      const float* krow = base + (size_t)(k0 + r) * (3 * DMODEL);
      Ks[c][r] = krow[DMODEL + hh * DHEAD + c];
      Vs[r][c] = krow[2 * DMODEL + hh * DHEAD + c];
    }
    __syncthreads();

    // S = (Q*scale) K^T  — 4x4 per thread
    float s[4][4] = {};
#pragma unroll
    for (int d = 0; d < 64; d++) {
      float a[4], bb[4];
#pragma unroll
      for (int i = 0; i < 4; i++) a[i] = Qs[d][tr * 4 + i];
#pragma unroll
      for (int j = 0; j < 4; j++) bb[j] = Ks[d][tc * 4 + j];
#pragma unroll
      for (int i = 0; i < 4; i++)
#pragma unroll
        for (int j = 0; j < 4; j++) s[i][j] += a[i] * bb[j];
    }
    if (kt == qt) {  // causal mask only on the diagonal tile
#pragma unroll
      for (int i = 0; i < 4; i++)
#pragma unroll
        for (int j = 0; j < 4; j++)
          if (k0 + tc * 4 + j > q0 + tr * 4 + i) s[i][j] = -3.4e38f;
    }

    // online softmax: the 16 lanes with equal tr share each q row
#pragma unroll
    for (int i = 0; i < 4; i++) {
      float rm = fmaxf(fmaxf(s[i][0], s[i][1]), fmaxf(s[i][2], s[i][3]));
#pragma unroll
      for (int off = 1; off < 16; off <<= 1) rm = fmaxf(rm, __shfl_xor(rm, off));
      float mnew = fmaxf(m_i[i], rm);
      float alpha = expf(m_i[i] - mnew);
      float p[4], rsum = 0.f;
#pragma unroll
      for (int j = 0; j < 4; j++) { p[j] = expf(s[i][j] - mnew); rsum += p[j]; }
#pragma unroll
      for (int off = 1; off < 16; off <<= 1) rsum += __shfl_xor(rsum, off);
      l_i[i] = l_i[i] * alpha + rsum;
      m_i[i] = mnew;
#pragma unroll
      for (int j = 0; j < 4; j++) {
        O[i][j] *= alpha;
        Ps[tr * 4 + i][tc * 4 + j] = p[j];
      }
    }
    __syncthreads();

    // O += P V — 4x4 per thread (same tr = same q rows, so alpha bookkeeping is consistent)
#pragma unroll
    for (int kk = 0; kk < 64; kk++) {
      float a[4], bb[4];
#pragma unroll
      for (int i = 0; i < 4; i++) a[i] = Ps[tr * 4 + i][kk];
#pragma unroll
      for (int j = 0; j < 4; j++) bb[j] = Vs[kk][tc * 4 + j];
#pragma unroll
      for (int i = 0; i < 4; i++)
#pragma unroll
        for (int j = 0; j < 4; j++) O[i][j] += a[i] * bb[j];
    }
  }

#pragma unroll
  for (int i = 0; i < 4; i++) {
    float rinv = 1.f / l_i[i];
    float* orow = out + (size_t)(n0 + q0 + tr * 4 + i) * DMODEL + hh * DHEAD;
#pragma unroll
    for (int j = 0; j < 4; j++) orow[tc * 4 + j] = O[i][j] * rinv;
  }
}

// ---------------- gate: 1 thread per token ----------------
__global__ __launch_bounds__(256) void gate_kernel(const float* __restrict__ xln,
    const float* __restrict__ gw, const float* __restrict__ gb,
    int* __restrict__ counts, int* __restrict__ entries, float* __restrict__ tokw) {
  int n = blockIdx.x * 256 + threadIdx.x;
  if (n >= NTOK) return;
  const float* xr = xln + (size_t)n * DMODEL;
  float gl[NEXP];
#pragma unroll
  for (int e = 0; e < NEXP; e++) gl[e] = gb[e];
  for (int dd = 0; dd < DMODEL; dd++) {
    float xv = xr[dd];
#pragma unroll
    for (int e = 0; e < NEXP; e++) gl[e] += xv * gw[dd * NEXP + e];
  }
  float mx = gl[0];
#pragma unroll
  for (int e = 1; e < NEXP; e++) mx = fmaxf(mx, gl[e]);
  float ex[NEXP];
#pragma unroll
  for (int e = 0; e < NEXP; e++) ex[e] = expf(gl[e] - mx);
  int i0 = 0; float v0 = ex[0];
#pragma unroll
  for (int e = 1; e < NEXP; e++) if (ex[e] > v0) { v0 = ex[e]; i0 = e; }
  int i1 = -1; float v1 = -1.f;
#pragma unroll
  for (int e = 0; e < NEXP; e++) if (e != i0 && ex[e] > v1) { v1 = ex[e]; i1 = e; }
  float wsum = v0 + v1;            // softmax denominator cancels in renorm
  float w0 = v0 / wsum, w1 = v1 / wsum;
  int p0 = atomicAdd(&counts[i0], 1);
  entries[i0 * NTOK + p0] = n * 2 + 0;
  tokw[n * 2 + 0] = w0;
  int p1 = atomicAdd(&counts[i1], 1);
  entries[i1 * NTOK + p1] = n * 2 + 1;
  tokw[n * 2 + 1] = w1;
}

__global__ void zero_counts(int* c) { if (threadIdx.x < NEXP) c[threadIdx.x] = 0; }

// ---------------- combine: h += eo[slot0] + eo[slot1] ----------------
__global__ __launch_bounds__(256) void combine_kernel(float* __restrict__ h,
                                                      const float* __restrict__ eo) {
  int i = blockIdx.x * 256 + threadIdx.x;
  int n = i / DMODEL, d = i - n * DMODEL;
  h[i] += eo[(size_t)(n * 2) * DMODEL + d] + eo[(size_t)(n * 2 + 1) * DMODEL + d];
}

extern "C" void kernel_launch(void* const* d_in, const int* in_sizes, int n_in,
                              void* d_out, int out_size, void* d_ws, size_t ws_size,
                              hipStream_t stream) {
  const int*   x       = (const int*)d_in[0];
  const float* tok_emb = (const float*)d_in[1];
  const float* pos_emb = (const float*)d_in[2];
  const float* ln1_g   = (const float*)d_in[3];
  const float* ln1_b   = (const float*)d_in[4];
  const float* qkv_w   = (const float*)d_in[5];
  const float* qkv_b   = (const float*)d_in[6];
  const float* proj_w  = (const float*)d_in[7];
  const float* proj_b  = (const float*)d_in[8];
  const float* ln2_g   = (const float*)d_in[9];
  const float* ln2_b   = (const float*)d_in[10];
  const float* gate_w  = (const float*)d_in[11];
  const float* gate_b  = (const float*)d_in[12];
  const float* w1      = (const float*)d_in[13];
  const float* b1      = (const float*)d_in[14];
  const float* w2      = (const float*)d_in[15];
  const float* b2      = (const float*)d_in[16];
  const float* lnf_g   = (const float*)d_in[17];
  const float* lnf_b   = (const float*)d_in[18];
  float* out = (float*)d_out;

  const size_t ND = (size_t)NTOK * DMODEL;            // 3,145,728 floats
  float* h    = (float*)d_ws;
  float* xln  = h + ND;
  float* R    = xln + ND;                              // qkv (3*ND) / H1 (2N*DHID)
  float* R2   = R + (size_t)2 * NTOK * DHID;           // attn_out (ND) / eo (2N*D)
  float* tokw = R2 + (size_t)2 * NTOK * DMODEL;
  int* counts  = (int*)(tokw + 2 * NTOK);
  int* entries = counts + NEXP;

  float* qkvbuf   = R;
  float* H1       = R;
  float* attn_out = R2;
  float* eo       = R2;

  dim3 blk(256);
  embed_kernel<<<ND / 256, blk, 0, stream>>>(x, tok_emb, pos_emb, h);
  for (int l = 0; l < NLAYER; l++) {
    ln_kernel<<<NTOK, blk, 0, stream>>>(h, ln1_g + l * DMODEL, ln1_b + l * DMODEL, xln);
    gemm_mfma<false, false><<<dim3(3 * DMODEL / BN, NTOK / BM), blk, 0, stream>>>(
        xln, qkv_w + (size_t)l * DMODEL * 3 * DMODEL, qkv_b + l * 3 * DMODEL,
        qkvbuf, NTOK, 3 * DMODEL, DMODEL);
    fattn_kernel<<<dim3(SEQ / 64, NHEAD, 4), blk, 0, stream>>>(qkvbuf, attn_out);
    gemm_mfma<false, true><<<dim3(DMODEL / BN, NTOK / BM), blk, 0, stream>>>(
        attn_out, proj_w + (size_t)l * DMODEL * DMODEL, proj_b + l * DMODEL,
        h, NTOK, DMODEL, DMODEL);
    ln_kernel<<<NTOK, blk, 0, stream>>>(h, ln2_g + l * DMODEL, ln2_b + l * DMODEL, xln);
    zero_counts<<<1, 64, 0, stream>>>(counts);
    gate_kernel<<<NTOK / 256, blk, 0, stream>>>(
        xln, gate_w + (size_t)l * DMODEL * NEXP, gate_b + l * NEXP, counts, entries, tokw);
    gemm_moe_mfma<true, false><<<dim3(DHID / BN, NTOK / BM, NEXP), blk, 0, stream>>>(
        xln, w1 + (size_t)l * NEXP * DMODEL * DHID, b1 + (size_t)l * NEXP * DHID,
        H1, entries, counts, tokw, DHID, DMODEL);
    gemm_moe_mfma<false, true><<<dim3(DMODEL / BN, NTOK / BM, NEXP), blk, 0, stream>>>(
        H1, w2 + (size_t)l * NEXP * DHID * DMODEL, b2 + (size_t)l * NEXP * DMODEL,
        eo, entries, counts, tokw, DMODEL, DHID);
    combine_kernel<<<ND / 256, blk, 0, stream>>>(h, eo);
  }
  ln_kernel<<<NTOK, blk, 0, stream>>>(h, lnf_g, lnf_b, xln);
  gemm_mfma<true, false><<<dim3(VOCAB / BN, NTOK / BM), blk, 0, stream>>>(
      xln, tok_emb, nullptr, out, NTOK, VOCAB, DMODEL);
}

// Round 6
// 3374.216 us; speedup vs baseline: 2.6110x; 1.2523x over previous
//
#include <hip/hip_runtime.h>
#include <cstdint>
#include <cstddef>

#define SEQ 1024
#define DMODEL 768
#define NHEAD 12
#define DHEAD 64
#define NLAYER 4
#define NEXP 8
#define DHID 1536
#define VOCAB 512
#define NTOK 4096   // B*S

typedef __attribute__((ext_vector_type(4))) float f32x4;
typedef __attribute__((ext_vector_type(8))) unsigned short us8v;
typedef __attribute__((ext_vector_type(4))) unsigned short us4v;
typedef __attribute__((ext_vector_type(8))) __bf16 bf16x8;
union FragU { us8v u; bf16x8 b; };

// ---------------- embed ----------------
__global__ __launch_bounds__(256) void embed_kernel(const int* __restrict__ x,
    const float* __restrict__ tok, const float* __restrict__ pos, float* __restrict__ h) {
  int i = blockIdx.x * 256 + threadIdx.x;  // over NTOK*DMODEL
  int n = i / DMODEL, d = i - n * DMODEL;
  int s = n & (SEQ - 1);
  h[i] = tok[(size_t)x[n] * DMODEL + d] + pos[(size_t)s * DMODEL + d];
}

// ---------------- layernorm (one block per row) ----------------
__global__ __launch_bounds__(256) void ln_kernel(const float* __restrict__ x,
    const float* __restrict__ g, const float* __restrict__ b, float* __restrict__ y) {
  int row = blockIdx.x;
  const float* xr = x + (size_t)row * DMODEL;
  int t = threadIdx.x;
  float v0 = xr[t], v1 = xr[t + 256], v2 = xr[t + 512];
  float s = v0 + v1 + v2;
  float s2 = v0 * v0 + v1 * v1 + v2 * v2;
  for (int off = 32; off; off >>= 1) { s += __shfl_down(s, off); s2 += __shfl_down(s2, off); }
  __shared__ float rs[4], rq[4];
  if ((t & 63) == 0) { rs[t >> 6] = s; rq[t >> 6] = s2; }
  __syncthreads();
  float S  = rs[0] + rs[1] + rs[2] + rs[3];
  float S2 = rq[0] + rq[1] + rq[2] + rq[3];
  float m = S * (1.f / DMODEL);
  float var = S2 * (1.f / DMODEL) - m * m;
  float r = rsqrtf(var + 1e-5f);
  float* yr = y + (size_t)row * DMODEL;
  yr[t]       = (v0 - m) * r * g[t]       + b[t];
  yr[t + 256] = (v1 - m) * r * g[t + 256] + b[t + 256];
  yr[t + 512] = (v2 - m) * r * g[t + 512] + b[t + 512];
}

// ---------------- split-bf16 MFMA GEMM machinery ----------------
// 128x128 tile, 256 threads = 4 waves (2x2), each wave owns a 64x64 sub-tile
// = 4x4 grid of 16x16 fragments. K-step 32. fp32 inputs are split on the fly
// into bf16 hi/lo during LDS staging; acc = Ah*Bh + Ah*Bl + Al*Bh (fp32 acc).
#define BM 128
#define BN 128
#define BK 32

__device__ __forceinline__ int chx(int row, int kb) {
  return row * 32 + ((kb ^ ((row >> 1) & 3)) << 3);   // ushort units, 16B chunks
}

__device__ __forceinline__ void cvt8(const f32x4 x0, const f32x4 x1, us8v& h, us8v& l) {
#pragma unroll
  for (int j = 0; j < 4; j++) {
    unsigned int bb = __float_as_uint(x0[j]);
    h[j] = (unsigned short)(bb >> 16);
    float fl = x0[j] - __uint_as_float(bb & 0xffff0000u);
    l[j] = (unsigned short)(__float_as_uint(fl) >> 16);
  }
#pragma unroll
  for (int j = 0; j < 4; j++) {
    unsigned int bb = __float_as_uint(x1[j]);
    h[4 + j] = (unsigned short)(bb >> 16);
    float fl = x1[j] - __uint_as_float(bb & 0xffff0000u);
    l[4 + j] = (unsigned short)(__float_as_uint(fl) >> 16);
  }
}

template<bool TRANSB, bool RESID>
__global__ __launch_bounds__(256, 2) void gemm_mfma(
    const float* __restrict__ A, const float* __restrict__ Bm,
    const float* __restrict__ bias, float* __restrict__ C,
    int M, int Nn, int K)
{
  __shared__ __align__(16) unsigned short AsH[BM * 32], AsL[BM * 32];
  __shared__ __align__(16) unsigned short BsH[BN * 32], BsL[BN * 32];
  int bm = blockIdx.y * BM, bn = blockIdx.x * BN;
  int tid = threadIdx.x;
  int lane = tid & 63;
  int wid = tid >> 6;
  int wr = wid >> 1, wc = wid & 1;
  int frow = lane & 15, fkb = lane >> 4;
  f32x4 zero = {0.f, 0.f, 0.f, 0.f};
  f32x4 acc[4][4];
#pragma unroll
  for (int i = 0; i < 4; i++)
#pragma unroll
    for (int j = 0; j < 4; j++) acc[i][j] = zero;

  int sr = tid & 127;          // staging row (A side) / col (B side)
  bool doB = tid >= 128;

  for (int k0 = 0; k0 < K; k0 += BK) {
    if (!doB) {
      const float* Ap = A + (size_t)(bm + sr) * K + k0;
#pragma unroll
      for (int c = 0; c < 4; c++) {
        f32x4 x0 = *(const f32x4*)(Ap + c * 8);
        f32x4 x1 = *(const f32x4*)(Ap + c * 8 + 4);
        us8v h, l; cvt8(x0, x1, h, l);
        *(us8v*)&AsH[chx(sr, c)] = h;
        *(us8v*)&AsL[chx(sr, c)] = l;
      }
    } else if (TRANSB) {
      const float* Bp = Bm + (size_t)(bn + sr) * K + k0;   // B^T: rows are n, k-contig
#pragma unroll
      for (int c = 0; c < 4; c++) {
        f32x4 x0 = *(const f32x4*)(Bp + c * 8);
        f32x4 x1 = *(const f32x4*)(Bp + c * 8 + 4);
        us8v h, l; cvt8(x0, x1, h, l);
        *(us8v*)&BsH[chx(sr, c)] = h;
        *(us8v*)&BsL[chx(sr, c)] = l;
      }
    } else {
      const float* Bp = Bm + (size_t)k0 * Nn + bn + sr;    // B[k][n]: gather a column
#pragma unroll
      for (int c = 0; c < 4; c++) {
        f32x4 x0, x1;
#pragma unroll
        for (int j = 0; j < 4; j++) x0[j] = Bp[(size_t)(c * 8 + j) * Nn];
#pragma unroll
        for (int j = 0; j < 4; j++) x1[j] = Bp[(size_t)(c * 8 + 4 + j) * Nn];
        us8v h, l; cvt8(x0, x1, h, l);
        *(us8v*)&BsH[chx(sr, c)] = h;
        *(us8v*)&BsL[chx(sr, c)] = l;
      }
    }
    __syncthreads();
    FragU ah[4], al[4], bh[4], bl[4];
#pragma unroll
    for (int i = 0; i < 4; i++) {
      ah[i].u = *(const us8v*)&AsH[chx(wr * 64 + i * 16 + frow, fkb)];
      al[i].u = *(const us8v*)&AsL[chx(wr * 64 + i * 16 + frow, fkb)];
      bh[i].u = *(const us8v*)&BsH[chx(wc * 64 + i * 16 + frow, fkb)];
      bl[i].u = *(const us8v*)&BsL[chx(wc * 64 + i * 16 + frow, fkb)];
    }
#pragma unroll
    for (int i = 0; i < 4; i++)
#pragma unroll
      for (int j = 0; j < 4; j++)
        acc[i][j] = __builtin_amdgcn_mfma_f32_16x16x32_bf16(ah[i].b, bh[j].b, acc[i][j], 0, 0, 0);
#pragma unroll
    for (int i = 0; i < 4; i++)
#pragma unroll
      for (int j = 0; j < 4; j++)
        acc[i][j] = __builtin_amdgcn_mfma_f32_16x16x32_bf16(ah[i].b, bl[j].b, acc[i][j], 0, 0, 0);
#pragma unroll
    for (int i = 0; i < 4; i++)
#pragma unroll
      for (int j = 0; j < 4; j++)
        acc[i][j] = __builtin_amdgcn_mfma_f32_16x16x32_bf16(al[i].b, bh[j].b, acc[i][j], 0, 0, 0);
    __syncthreads();
  }
#pragma unroll
  for (int i = 0; i < 4; i++) {
    int rbase = bm + wr * 64 + i * 16 + (lane >> 4) * 4;
#pragma unroll
    for (int q = 0; q < 4; q++) {
      float* Crow = C + (size_t)(rbase + q) * Nn;
#pragma unroll
      for (int j = 0; j < 4; j++) {
        int col = bn + wc * 64 + j * 16 + frow;
        float v = acc[i][j][q] + (bias ? bias[col] : 0.f);
        if (RESID) v += Crow[col];
        Crow[col] = v;
      }
    }
  }
}

// ---------------- MoE gathered split-bf16 MFMA GEMM ----------------
__device__ __forceinline__ float gelu_f(float x) {
  float x3 = x * x * x;
  return 0.5f * x * (1.f + tanhf(0.7978845608028654f * (x + 0.044715f * x3)));
}

template<bool GELU, bool SCALE>
__global__ __launch_bounds__(256, 2) void gemm_moe_mfma(
    const float* __restrict__ A, const float* __restrict__ Bbase,
    const float* __restrict__ biasBase, float* __restrict__ C,
    const int* __restrict__ entries, const int* __restrict__ counts,
    const float* __restrict__ tokw, int Nn, int K)
{
  int e = blockIdx.z;
  int cnt = counts[e];
  int bm = blockIdx.y * BM;
  if (bm >= cnt) return;
  const float* Bm = Bbase + (size_t)e * K * Nn;
  const float* bias = biasBase + (size_t)e * Nn;
  const int* list = entries + e * NTOK;
  int bn = blockIdx.x * BN;
  int tid = threadIdx.x;
  int lane = tid & 63;
  int wid = tid >> 6;
  int wr = wid >> 1, wc = wid & 1;
  int frow = lane & 15, fkb = lane >> 4;

  __shared__ __align__(16) unsigned short AsH[BM * 32], AsL[BM * 32];
  __shared__ __align__(16) unsigned short BsH[BN * 32], BsL[BN * 32];
  __shared__ int rowent[BM];
  if (tid < BM) {
    int gr = bm + tid;
    rowent[tid] = (gr < cnt) ? list[gr] : -1;
  }
  __syncthreads();

  f32x4 zero = {0.f, 0.f, 0.f, 0.f};
  f32x4 acc[4][4];
#pragma unroll
  for (int i = 0; i < 4; i++)
#pragma unroll
    for (int j = 0; j < 4; j++) acc[i][j] = zero;

  int sr = tid & 127;
  bool doB = tid >= 128;

  for (int k0 = 0; k0 < K; k0 += BK) {
    if (!doB) {
      int ent = rowent[sr];
      if (ent >= 0) {
        int arow = GELU ? (ent >> 1) : ent;  // w1 gathers token rows, w2 gathers H1 rows
        const float* Ap = A + (size_t)arow * K + k0;
#pragma unroll
        for (int c = 0; c < 4; c++) {
          f32x4 x0 = *(const f32x4*)(Ap + c * 8);
          f32x4 x1 = *(const f32x4*)(Ap + c * 8 + 4);
          us8v h, l; cvt8(x0, x1, h, l);
          *(us8v*)&AsH[chx(sr, c)] = h;
          *(us8v*)&AsL[chx(sr, c)] = l;
        }
      } else {
        us8v z = {0, 0, 0, 0, 0, 0, 0, 0};
#pragma unroll
        for (int c = 0; c < 4; c++) {
          *(us8v*)&AsH[chx(sr, c)] = z;
          *(us8v*)&AsL[chx(sr, c)] = z;
        }
      }
    } else {
      const float* Bp = Bm + (size_t)k0 * Nn + bn + sr;
#pragma unroll
      for (int c = 0; c < 4; c++) {
        f32x4 x0, x1;
#pragma unroll
        for (int j = 0; j < 4; j++) x0[j] = Bp[(size_t)(c * 8 + j) * Nn];
#pragma unroll
        for (int j = 0; j < 4; j++) x1[j] = Bp[(size_t)(c * 8 + 4 + j) * Nn];
        us8v h, l; cvt8(x0, x1, h, l);
        *(us8v*)&BsH[chx(sr, c)] = h;
        *(us8v*)&BsL[chx(sr, c)] = l;
      }
    }
    __syncthreads();
    FragU ah[4], al[4], bh[4], bl[4];
#pragma unroll
    for (int i = 0; i < 4; i++) {
      ah[i].u = *(const us8v*)&AsH[chx(wr * 64 + i * 16 + frow, fkb)];
      al[i].u = *(const us8v*)&AsL[chx(wr * 64 + i * 16 + frow, fkb)];
      bh[i].u = *(const us8v*)&BsH[chx(wc * 64 + i * 16 + frow, fkb)];
      bl[i].u = *(const us8v*)&BsL[chx(wc * 64 + i * 16 + frow, fkb)];
    }
#pragma unroll
    for (int i = 0; i < 4; i++)
#pragma unroll
      for (int j = 0; j < 4; j++)
        acc[i][j] = __builtin_amdgcn_mfma_f32_16x16x32_bf16(ah[i].b, bh[j].b, acc[i][j], 0, 0, 0);
#pragma unroll
    for (int i = 0; i < 4; i++)
#pragma unroll
      for (int j = 0; j < 4; j++)
        acc[i][j] = __builtin_amdgcn_mfma_f32_16x16x32_bf16(ah[i].b, bl[j].b, acc[i][j], 0, 0, 0);
#pragma unroll
    for (int i = 0; i < 4; i++)
#pragma unroll
      for (int j = 0; j < 4; j++)
        acc[i][j] = __builtin_amdgcn_mfma_f32_16x16x32_bf16(al[i].b, bh[j].b, acc[i][j], 0, 0, 0);
    __syncthreads();
  }
#pragma unroll
  for (int i = 0; i < 4; i++) {
    int rloc = wr * 64 + i * 16 + (lane >> 4) * 4;
#pragma unroll
    for (int q = 0; q < 4; q++) {
      int ent = rowent[rloc + q];
      if (ent < 0) continue;
      float scl = SCALE ? tokw[ent] : 1.f;
      float* Crow = C + (size_t)ent * Nn;
#pragma unroll
      for (int j = 0; j < 4; j++) {
        int col = bn + wc * 64 + j * 16 + frow;
        float v = acc[i][j][q] + bias[col];
        if (GELU) v = gelu_f(v);
        if (SCALE) v *= scl;
        Crow[col] = v;
      }
    }
  }
}

// ---------------- MFMA flash attention — BISECTION BUILD ----------------
// Round 3/5 failed with IDENTICAL absmax with/without the P-ordering barrier
// -> deterministic logic bug, location unknown. This build keeps the FRONT
// half (Q-in-registers, K hi/lo swizzled LDS, 3-MFMA QK^T, mask, online
// softmax in the MFMA C-frame) and replaces the BACK half with known-good
// round-2 machinery: P stored fp32 (Psf), V staged plain fp32 (Vs[k][d]),
// PV computed on the VALU. PASS -> bug was in {bf16-P/Pw A-frag, Vt
// transpose, PV MFMA}. FAIL@1.3477 -> bug in QK^T/softmax/mask.
__device__ __forceinline__ int kvx(int row, int col) {   // ushort units; rows of 64
  return (row << 6) + (((((col >> 3) ^ (row & 7))) << 3) | (col & 7));
}

__global__ __launch_bounds__(256, 2) void fattn_mfma(const float* __restrict__ qkv,
                                                     float* __restrict__ out) {
  int qt = blockIdx.x;           // q tile 0..15
  int hh = blockIdx.y;           // head
  int b  = blockIdx.z;           // batch
  int n0 = b * SEQ;
  int q0 = qt * 64;
  const float* base = qkv + (size_t)n0 * (3 * DMODEL);
  int tid = threadIdx.x;
  int lane = tid & 63;
  int w = tid >> 6;
  int fr = lane & 15, fg = lane >> 4;

  __shared__ __align__(16) unsigned short KsH[64 * 64], KsL[64 * 64];
  __shared__ float Vs[64][64];     // fp32 V[k][d], round-2 staging pattern
  __shared__ float Psf[4][16][68]; // fp32 P[q(wave-local)][key], per wave

  // Q fragments (A-operand), pre-scaled by 1/8, split hi/lo in registers
  FragU qh[2], ql[2];
  {
    const float* qrow = base + (size_t)(q0 + w * 16 + fr) * (3 * DMODEL) + hh * DHEAD;
#pragma unroll
    for (int s = 0; s < 2; s++) {
      f32x4 x0 = *(const f32x4*)(qrow + s * 32 + fg * 8);
      f32x4 x1 = *(const f32x4*)(qrow + s * 32 + fg * 8 + 4);
      x0 *= 0.125f; x1 *= 0.125f;
      cvt8(x0, x1, qh[s].u, ql[s].u);
    }
  }

  f32x4 O[4];
  float m_i[4], l_i[4];
#pragma unroll
  for (int c = 0; c < 4; c++) O[c] = (f32x4){0.f, 0.f, 0.f, 0.f};
#pragma unroll
  for (int r = 0; r < 4; r++) { m_i[r] = -3.4e38f; l_i[r] = 0.f; }

  int krow = tid >> 2, kd = (tid & 3) << 4;            // K staging: row, 16-float d-chunk

  for (int kt = 0; kt <= qt; kt++) {
    int k0 = kt * 64;
    __syncthreads();   // previous tile's Ks/Vs/Psf reads done
    {  // stage K hi/lo
      const float* kp = base + (size_t)(k0 + krow) * (3 * DMODEL) + DMODEL + hh * DHEAD + kd;
      f32x4 x0 = *(const f32x4*)(kp);
      f32x4 x1 = *(const f32x4*)(kp + 4);
      f32x4 x2 = *(const f32x4*)(kp + 8);
      f32x4 x3 = *(const f32x4*)(kp + 12);
      us8v h0, l0, h1, l1;
      cvt8(x0, x1, h0, l0); cvt8(x2, x3, h1, l1);
      *(us8v*)&KsH[kvx(krow, kd)]     = h0;
      *(us8v*)&KsH[kvx(krow, kd + 8)] = h1;
      *(us8v*)&KsL[kvx(krow, kd)]     = l0;
      *(us8v*)&KsL[kvx(krow, kd + 8)] = l1;
    }
    {  // stage V fp32 (round-2 pattern)
#pragma unroll
      for (int it = 0; it < 16; it++) {
        int i = tid + it * 256;
        int r = i >> 6, c = i & 63;
        Vs[r][c] = base[(size_t)(k0 + r) * (3 * DMODEL) + 2 * DMODEL + hh * DHEAD + c];
      }
    }
    __syncthreads();

    // S = (Q/8) K^T : 4 key-frags x 2 k-steps x 3-MFMA split
    f32x4 sa[4];
#pragma unroll
    for (int f = 0; f < 4; f++) sa[f] = (f32x4){0.f, 0.f, 0.f, 0.f};
#pragma unroll
    for (int s = 0; s < 2; s++) {
#pragma unroll
      for (int f = 0; f < 4; f++) {
        FragU kh, kl;
        kh.u = *(const us8v*)&KsH[kvx(f * 16 + fr, s * 32 + fg * 8)];
        kl.u = *(const us8v*)&KsL[kvx(f * 16 + fr, s * 32 + fg * 8)];
        sa[f] = __builtin_amdgcn_mfma_f32_16x16x32_bf16(qh[s].b, kh.b, sa[f], 0, 0, 0);
        sa[f] = __builtin_amdgcn_mfma_f32_16x16x32_bf16(qh[s].b, kl.b, sa[f], 0, 0, 0);
        sa[f] = __builtin_amdgcn_mfma_f32_16x16x32_bf16(ql[s].b, kh.b, sa[f], 0, 0, 0);
      }
    }
    if (kt == qt) {  // causal mask on the diagonal tile: key > q  -> -inf
#pragma unroll
      for (int f = 0; f < 4; f++)
#pragma unroll
        for (int r = 0; r < 4; r++)
          if (k0 + f * 16 + fr > q0 + w * 16 + fg * 4 + r) sa[f][r] = -3.4e38f;
    }

    // online softmax; S layout: row q = fg*4+r (wave-local), col key = f*16+fr
#pragma unroll
    for (int r = 0; r < 4; r++) {
      float rm = fmaxf(fmaxf(sa[0][r], sa[1][r]), fmaxf(sa[2][r], sa[3][r]));
      rm = fmaxf(rm, __shfl_xor(rm, 1));
      rm = fmaxf(rm, __shfl_xor(rm, 2));
      rm = fmaxf(rm, __shfl_xor(rm, 4));
      rm = fmaxf(rm, __shfl_xor(rm, 8));
      float mnew = fmaxf(m_i[r], rm);
      float alpha = __expf(m_i[r] - mnew);
      m_i[r] = mnew;
      float rsum = 0.f;
#pragma unroll
      for (int f = 0; f < 4; f++) {
        float p = __expf(sa[f][r] - mnew);
        rsum += p;
        Psf[w][fg * 4 + r][f * 16 + fr] = p;
      }
      rsum += __shfl_xor(rsum, 1);
      rsum += __shfl_xor(rsum, 2);
      rsum += __shfl_xor(rsum, 4);
      rsum += __shfl_xor(rsum, 8);
      l_i[r] = l_i[r] * alpha + rsum;
#pragma unroll
      for (int c = 0; c < 4; c++) O[c][r] *= alpha;
    }
    __syncthreads();   // order cross-lane P stores before PV reads

    // O += P V  — VALU (round-2 machinery re-indexed to this thread mapping)
    for (int kk = 0; kk < 64; kk++) {
      float pr[4], vv[4];
#pragma unroll
      for (int r = 0; r < 4; r++) pr[r] = Psf[w][fg * 4 + r][kk];
#pragma unroll
      for (int c = 0; c < 4; c++) vv[c] = Vs[kk][c * 16 + fr];
#pragma unroll
      for (int c = 0; c < 4; c++)
#pragma unroll
        for (int r = 0; r < 4; r++) O[c][r] += pr[r] * vv[c];
    }
  }

#pragma unroll
  for (int r = 0; r < 4; r++) {
    float rinv = 1.f / l_i[r];
    float* orow = out + (size_t)(n0 + q0 + w * 16 + fg * 4 + r) * DMODEL + hh * DHEAD;
#pragma unroll
    for (int c = 0; c < 4; c++) orow[c * 16 + fr] = O[c][r] * rinv;
  }
}

// ---------------- gate: 1 thread per token ----------------
__global__ __launch_bounds__(256) void gate_kernel(const float* __restrict__ xln,
    const float* __restrict__ gw, const float* __restrict__ gb,
    int* __restrict__ counts, int* __restrict__ entries, float* __restrict__ tokw) {
  int n = blockIdx.x * 256 + threadIdx.x;
  if (n >= NTOK) return;
  const float* xr = xln + (size_t)n * DMODEL;
  float gl[NEXP];
#pragma unroll
  for (int e = 0; e < NEXP; e++) gl[e] = gb[e];
  for (int dd = 0; dd < DMODEL; dd++) {
    float xv = xr[dd];
#pragma unroll
    for (int e = 0; e < NEXP; e++) gl[e] += xv * gw[dd * NEXP + e];
  }
  float mx = gl[0];
#pragma unroll
  for (int e = 1; e < NEXP; e++) mx = fmaxf(mx, gl[e]);
  float ex[NEXP];
#pragma unroll
  for (int e = 0; e < NEXP; e++) ex[e] = expf(gl[e] - mx);
  int i0 = 0; float v0 = ex[0];
#pragma unroll
  for (int e = 1; e < NEXP; e++) if (ex[e] > v0) { v0 = ex[e]; i0 = e; }
  int i1 = -1; float v1 = -1.f;
#pragma unroll
  for (int e = 0; e < NEXP; e++) if (e != i0 && ex[e] > v1) { v1 = ex[e]; i1 = e; }
  float wsum = v0 + v1;            // softmax denominator cancels in renorm
  float w0 = v0 / wsum, w1 = v1 / wsum;
  int p0 = atomicAdd(&counts[i0], 1);
  entries[i0 * NTOK + p0] = n * 2 + 0;
  tokw[n * 2 + 0] = w0;
  int p1 = atomicAdd(&counts[i1], 1);
  entries[i1 * NTOK + p1] = n * 2 + 1;
  tokw[n * 2 + 1] = w1;
}

__global__ void zero_counts(int* c) { if (threadIdx.x < NEXP) c[threadIdx.x] = 0; }

// ---------------- combine: h += eo[slot0] + eo[slot1] ----------------
__global__ __launch_bounds__(256) void combine_kernel(float* __restrict__ h,
                                                      const float* __restrict__ eo) {
  int i = blockIdx.x * 256 + threadIdx.x;
  int n = i / DMODEL, d = i - n * DMODEL;
  h[i] += eo[(size_t)(n * 2) * DMODEL + d] + eo[(size_t)(n * 2 + 1) * DMODEL + d];
}

extern "C" void kernel_launch(void* const* d_in, const int* in_sizes, int n_in,
                              void* d_out, int out_size, void* d_ws, size_t ws_size,
                              hipStream_t stream) {
  const int*   x       = (const int*)d_in[0];
  const float* tok_emb = (const float*)d_in[1];
  const float* pos_emb = (const float*)d_in[2];
  const float* ln1_g   = (const float*)d_in[3];
  const float* ln1_b   = (const float*)d_in[4];
  const float* qkv_w   = (const float*)d_in[5];
  const float* qkv_b   = (const float*)d_in[6];
  const float* proj_w  = (const float*)d_in[7];
  const float* proj_b  = (const float*)d_in[8];
  const float* ln2_g   = (const float*)d_in[9];
  const float* ln2_b   = (const float*)d_in[10];
  const float* gate_w  = (const float*)d_in[11];
  const float* gate_b  = (const float*)d_in[12];
  const float* w1      = (const float*)d_in[13];
  const float* b1      = (const float*)d_in[14];
  const float* w2      = (const float*)d_in[15];
  const float* b2      = (const float*)d_in[16];
  const float* lnf_g   = (const float*)d_in[17];
  const float* lnf_b   = (const float*)d_in[18];
  float* out = (float*)d_out;

  const size_t ND = (size_t)NTOK * DMODEL;            // 3,145,728 floats
  float* h    = (float*)d_ws;
  float* xln  = h + ND;
  float* R    = xln + ND;                              // qkv (3*ND) / H1 (2N*DHID)
  float* R2   = R + (size_t)2 * NTOK * DHID;           // attn_out (ND) / eo (2N*D)
  float* tokw = R2 + (size_t)2 * NTOK * DMODEL;
  int* counts  = (int*)(tokw + 2 * NTOK);
  int* entries = counts + NEXP;

  float* qkvbuf   = R;
  float* H1       = R;
  float* attn_out = R2;
  float* eo       = R2;

  dim3 blk(256);
  embed_kernel<<<ND / 256, blk, 0, stream>>>(x, tok_emb, pos_emb, h);
  for (int l = 0; l < NLAYER; l++) {
    ln_kernel<<<NTOK, blk, 0, stream>>>(h, ln1_g + l * DMODEL, ln1_b + l * DMODEL, xln);
    gemm_mfma<false, false><<<dim3(3 * DMODEL / BN, NTOK / BM), blk, 0, stream>>>(
        xln, qkv_w + (size_t)l * DMODEL * 3 * DMODEL, qkv_b + l * 3 * DMODEL,
        qkvbuf, NTOK, 3 * DMODEL, DMODEL);
    fattn_mfma<<<dim3(SEQ / 64, NHEAD, 4), blk, 0, stream>>>(qkvbuf, attn_out);
    gemm_mfma<false, true><<<dim3(DMODEL / BN, NTOK / BM), blk, 0, stream>>>(
        attn_out, proj_w + (size_t)l * DMODEL * DMODEL, proj_b + l * DMODEL,
        h, NTOK, DMODEL, DMODEL);
    ln_kernel<<<NTOK, blk, 0, stream>>>(h, ln2_g + l * DMODEL, ln2_b + l * DMODEL, xln);
    zero_counts<<<1, 64, 0, stream>>>(counts);
    gate_kernel<<<NTOK / 256, blk, 0, stream>>>(
        xln, gate_w + (size_t)l * DMODEL * NEXP, gate_b + l * NEXP, counts, entries, tokw);
    gemm_moe_mfma<true, false><<<dim3(DHID / BN, NTOK / BM, NEXP), blk, 0, stream>>>(
        xln, w1 + (size_t)l * NEXP * DMODEL * DHID, b1 + (size_t)l * NEXP * DHID,
        H1, entries, counts, tokw, DHID, DMODEL);
    gemm_moe_mfma<false, true><<<dim3(DMODEL / BN, NTOK / BM, NEXP), blk, 0, stream>>>(
        H1, w2 + (size_t)l * NEXP * DHID * DMODEL, b2 + (size_t)l * NEXP * DMODEL,
        eo, entries, counts, tokw, DMODEL, DHID);
    combine_kernel<<<ND / 256, blk, 0, stream>>>(h, eo);
  }
  ln_kernel<<<NTOK, blk, 0, stream>>>(h, lnf_g, lnf_b, xln);
  gemm_mfma<true, false><<<dim3(VOCAB / BN, NTOK / BM), blk, 0, stream>>>(
      xln, tok_emb, nullptr, out, NTOK, VOCAB, DMODEL);
}